// Round 5
// baseline (907.035 us; speedup 1.0000x reference)
//
#include <hip/hip_runtime.h>
#include <hip/hip_bf16.h>

#define NN 100000
#define NE 1600000
// D_H = D_E = D_Q = 64, D_HID = 128, N_GRAPHS = 16

typedef __attribute__((ext_vector_type(8))) unsigned short ushort8v;
typedef __attribute__((ext_vector_type(8))) short short8v;
typedef __attribute__((ext_vector_type(4))) float f32x4;

__device__ __forceinline__ float b2f(unsigned short u) {
  return __uint_as_float(((unsigned)u) << 16);
}
// f32 -> bf16 bits, round-to-nearest-even
__device__ __forceinline__ short f2bs(float f) {
  unsigned u = __float_as_uint(f);
  unsigned r = (u + 0x7FFFu + ((u >> 16) & 1u)) >> 16;
  return (short)r;
}

// Qg[g][j] = gate_b1[j] + sum_k q[g][k] * gate_w1[128+k][j]
__global__ void qproj_kernel(const float* __restrict__ q,
                             const float* __restrict__ gw1,
                             const float* __restrict__ gb1,
                             float* __restrict__ Qg) {
  int g = blockIdx.x, j = threadIdx.x;
  float acc = gb1[j];
  for (int k = 0; k < 64; ++k) acc += q[g * 64 + k] * gw1[(128 + k) * 128 + j];
  Qg[g * 128 + j] = acc;
}

// Prepack score_w1 e-part (rows 128..191) into bf16 MFMA B-fragments.
// Fragment (t, ks), lane l=(qg,cl): elem j = sw1[(128+ks*32+qg*8+j)*128 + t*16+cl]
__global__ __launch_bounds__(1024) void prepack_kernel(
    const float* __restrict__ sw1, short8v* __restrict__ WtG) {
  int tid = threadIdx.x;
  int t = tid >> 7, ks = (tid >> 6) & 1, lane = tid & 63;
  int qg = lane >> 4, cl = lane & 15;
  short8v fr;
#pragma unroll
  for (int j = 0; j < 8; ++j)
    fr[j] = f2bs(sw1[(128 + ks * 32 + qg * 8 + j) * 128 + t * 16 + cl]);
  WtG[tid] = fr;
}

// Node projections -> 4 separate bf16 arrays [N][128]:
// part 0: GA = h @ gw1[r0..63]    part 1: SA = h @ sw1[r0..63]
// part 2: GB = h @ gw1[r64..127]  part 3: SB = h @ sw1[r64..127]
__global__ __launch_bounds__(256) void nodeproj_kernel(
    const float* __restrict__ h, const float* __restrict__ gw1,
    const float* __restrict__ sw1, __hip_bfloat16* __restrict__ GA,
    __hip_bfloat16* __restrict__ GB, __hip_bfloat16* __restrict__ SA,
    __hip_bfloat16* __restrict__ SB) {
  __shared__ float hs[64][64];   // [k][n]
  __shared__ float Ws[64][128];  // [k][c]
  int part = blockIdx.y;
  const float* W = (part & 1) ? sw1 : gw1;
  int roff = (part >= 2) ? 64 : 0;
  __hip_bfloat16* outp = (part == 0) ? GA : (part == 1) ? SA : (part == 2) ? GB : SB;
  int n0 = blockIdx.x * 64;
  int t = threadIdx.x;

  {
    int n = t & 63, kc = t >> 6;
    int gn = n0 + n;
#pragma unroll
    for (int i = 0; i < 4; ++i) {
      int k = kc * 16 + i * 4;
      float4 hv = make_float4(0.f, 0.f, 0.f, 0.f);
      if (gn < NN) hv = *(const float4*)&h[gn * 64 + k];
      hs[k + 0][n] = hv.x; hs[k + 1][n] = hv.y;
      hs[k + 2][n] = hv.z; hs[k + 3][n] = hv.w;
    }
  }
  {
    const float* Wb = W + roff * 128;
    float* wsf = &Ws[0][0];
#pragma unroll
    for (int i = 0; i < 8; ++i) {
      int flat = (i * 256 + t) * 4;
      *(float4*)&wsf[flat] = *(const float4*)&Wb[flat];
    }
  }
  __syncthreads();

  int tx = t & 31, ty = t >> 5;
  float acc[8][4] = {};
#pragma unroll 4
  for (int k = 0; k < 64; ++k) {
    float hn[8];
    *(float4*)&hn[0] = *(const float4*)&hs[k][ty * 8];
    *(float4*)&hn[4] = *(const float4*)&hs[k][ty * 8 + 4];
    float wv[4];
#pragma unroll
    for (int i = 0; i < 4; ++i) wv[i] = Ws[k][tx + 32 * i];
#pragma unroll
    for (int j = 0; j < 8; ++j)
#pragma unroll
      for (int i = 0; i < 4; ++i) acc[j][i] += hn[j] * wv[i];
  }
#pragma unroll
  for (int j = 0; j < 8; ++j) {
    int gn = n0 + ty * 8 + j;
    if (gn < NN) {
#pragma unroll
      for (int i = 0; i < 4; ++i)
        outp[(size_t)gn * 128 + tx + 32 * i] = __float2bfloat16(acc[j][i]);
    }
  }
}

// Gate kernel: one thread per edge; hot set = GA+GB (51MB) only.
__global__ __launch_bounds__(256) void gate_kernel(
    const int* __restrict__ eidx, const int* __restrict__ ebat,
    const __hip_bfloat16* __restrict__ GA, const __hip_bfloat16* __restrict__ GB,
    const float* __restrict__ Qg, const float* __restrict__ gw2,
    const float* __restrict__ gb2, float* __restrict__ gate) {
  int ee = blockIdx.x * 256 + threadIdx.x;
  int src = eidx[ee], dst = eidx[NE + ee], g = ebat[ee];
  const ushort8v* ga = (const ushort8v*)((const unsigned short*)GA + (size_t)src * 128);
  const ushort8v* gb = (const ushort8v*)((const unsigned short*)GB + (size_t)dst * 128);
  const f32x4* qv = (const f32x4*)(Qg + g * 128);
  const f32x4* w2 = (const f32x4*)gw2;
  float gacc = 0.f;
#pragma unroll
  for (int jo = 0; jo < 16; ++jo) {
    ushort8v av = ga[jo], bv = gb[jo];
#pragma unroll
    for (int half = 0; half < 2; ++half) {
      f32x4 qq = qv[2 * jo + half];
      f32x4 ww = w2[2 * jo + half];
#pragma unroll
      for (int ii = 0; ii < 4; ++ii) {
        float x = b2f(av[half * 4 + ii]) + b2f(bv[half * 4 + ii]) + qq[ii];
        gacc = fmaf(fmaxf(x, 0.f), ww[ii], gacc);
      }
    }
  }
  gate[ee] = 1.f / (1.f + __expf(-(gacc + gb2[0])));
}

// Score kernel (r3 structure): 4 waves x 64 edges; B-frags from prepacked
// global (coalesced); rt-outer MFMA; epilogue 16-lane shared-row gathers;
// fused exp + atomicAdd(nsum); writes exp(raw) to out.
__global__ __launch_bounds__(256) void score_kernel(
    const float* __restrict__ e, const int* __restrict__ eidx,
    const __hip_bfloat16* __restrict__ SA, const __hip_bfloat16* __restrict__ SB,
    const short8v* __restrict__ WtG, const float* __restrict__ sb1,
    const float* __restrict__ sw2, const float* __restrict__ sb2,
    const float* __restrict__ gate, float* __restrict__ out,
    float* __restrict__ nsum) {
  const int tid = threadIdx.x;
  const int w = tid >> 6, lane = tid & 63;
  const int qg = lane >> 4, cl = lane & 15;
  const int EB = blockIdx.x * 256 + w * 64;
  const unsigned short* SAU = (const unsigned short*)SA;
  const unsigned short* SBU = (const unsigned short*)SB;
  const float sb2v = sb2[0];

  // B fragments from prepack: 16 coalesced 16B loads (L2-hot, all blocks share)
  short8v Bf[8][2];
#pragma unroll
  for (int t = 0; t < 8; ++t)
#pragma unroll
    for (int ks = 0; ks < 2; ++ks) Bf[t][ks] = WtG[(t * 2 + ks) * 64 + lane];

  float sbv[8], s2v[8];
#pragma unroll
  for (int t = 0; t < 8; ++t) {
    sbv[t] = sb1[t * 16 + cl];
    s2v[t] = sw2[t * 16 + cl];
  }

#pragma unroll 1
  for (int rt = 0; rt < 4; ++rt) {
    // A fragments: row = cl (edge EB+rt*16+cl), k = ks*32 + qg*8 + j
    int arow = EB + rt * 16 + cl;
    const float* ap = e + (size_t)arow * 64 + qg * 8;
    f32x4 f0 = __builtin_nontemporal_load((const f32x4*)(ap + 0));
    f32x4 f1 = __builtin_nontemporal_load((const f32x4*)(ap + 4));
    f32x4 f2 = __builtin_nontemporal_load((const f32x4*)(ap + 32));
    f32x4 f3 = __builtin_nontemporal_load((const f32x4*)(ap + 36));
    short8v a0, a1;
    a0[0] = f2bs(f0.x); a0[1] = f2bs(f0.y); a0[2] = f2bs(f0.z); a0[3] = f2bs(f0.w);
    a0[4] = f2bs(f1.x); a0[5] = f2bs(f1.y); a0[6] = f2bs(f1.z); a0[7] = f2bs(f1.w);
    a1[0] = f2bs(f2.x); a1[1] = f2bs(f2.y); a1[2] = f2bs(f2.z); a1[3] = f2bs(f2.w);
    a1[4] = f2bs(f3.x); a1[5] = f2bs(f3.y); a1[6] = f2bs(f3.z); a1[7] = f2bs(f3.w);

    f32x4 acc[8];
#pragma unroll
    for (int t = 0; t < 8; ++t) {
      acc[t] = (f32x4){0.f, 0.f, 0.f, 0.f};
      acc[t] = __builtin_amdgcn_mfma_f32_16x16x32_bf16(a0, Bf[t][0], acc[t], 0, 0, 0);
      acc[t] = __builtin_amdgcn_mfma_f32_16x16x32_bf16(a1, Bf[t][1], acc[t], 0, 0, 0);
    }

    // epilogue: C layout col = cl (hidden 16t+cl), row = qg*4 + i (edge)
    int srcv[4], dstv[4];
#pragma unroll
    for (int i = 0; i < 4; ++i) {
      int E = EB + rt * 16 + qg * 4 + i;
      srcv[i] = eidx[E];
      dstv[i] = eidx[NE + E];
    }
    float part[4] = {0.f, 0.f, 0.f, 0.f};
#pragma unroll
    for (int t = 0; t < 8; ++t) {
      int col = t * 16 + cl;
#pragma unroll
      for (int i = 0; i < 4; ++i) {
        float sa = b2f(SAU[(size_t)srcv[i] * 128 + col]);
        float sb = b2f(SBU[(size_t)dstv[i] * 128 + col]);
        float hv = acc[t][i] + sa + sb + sbv[t];
        part[i] = fmaf(fmaxf(hv, 0.f), s2v[t], part[i]);
      }
    }
#pragma unroll
    for (int m = 1; m < 16; m <<= 1)
#pragma unroll
      for (int i = 0; i < 4; ++i) part[i] += __shfl_xor(part[i], m, 64);

    if (cl < 4) {
      int r = rt * 16 + qg * 4 + cl;
      int E = EB + r;
      float p = (cl == 0) ? part[0] : (cl == 1) ? part[1] : (cl == 2) ? part[2] : part[3];
      int d   = (cl == 0) ? dstv[0] : (cl == 1) ? dstv[1] : (cl == 2) ? dstv[2] : dstv[3];
      float ex = __expf(gate[E] * (p + sb2v));
      out[E] = ex;
      atomicAdd(&nsum[d], ex);
    }
  }
}

__global__ __launch_bounds__(256) void norm_kernel(
    const int* __restrict__ eidx, const float* __restrict__ nodesum,
    float* __restrict__ out) {
  int ee = blockIdx.x * 256 + threadIdx.x;
  int dst = eidx[NE + ee];
  out[ee] = out[ee] / fmaxf(nodesum[dst], 1e-9f);
}

extern "C" void kernel_launch(void* const* d_in, const int* in_sizes, int n_in,
                              void* d_out, int out_size, void* d_ws, size_t ws_size,
                              hipStream_t stream) {
  const float* h   = (const float*)d_in[0];
  const float* e   = (const float*)d_in[1];
  const float* q   = (const float*)d_in[2];
  const int* eidx  = (const int*)d_in[3];
  const int* ebat  = (const int*)d_in[4];
  const float* gw1 = (const float*)d_in[5];
  const float* gb1 = (const float*)d_in[6];
  const float* gw2 = (const float*)d_in[7];
  const float* gb2 = (const float*)d_in[8];
  const float* sw1 = (const float*)d_in[9];
  const float* sb1 = (const float*)d_in[10];
  const float* sw2 = (const float*)d_in[11];
  const float* sb2 = (const float*)d_in[12];
  float* out = (float*)d_out;

  char* ws = (char*)d_ws;
  // 4 x 25.6MB projections | Qg 8KB | WtG 16KB | gate 6.4MB | nsum 400KB
  __hip_bfloat16* GA = (__hip_bfloat16*)ws;
  __hip_bfloat16* GB = (__hip_bfloat16*)(ws + 25600000);
  __hip_bfloat16* SA = (__hip_bfloat16*)(ws + 51200000);
  __hip_bfloat16* SB = (__hip_bfloat16*)(ws + 76800000);
  float* Qg    = (float*)(ws + 102400000);
  short8v* WtG = (short8v*)(ws + 102400000 + 8192);
  float* gateb = (float*)(ws + 102400000 + 8192 + 16384);
  float* nsum  = (float*)(ws + 102400000 + 8192 + 16384 + 6400000);

  (void)hipMemsetAsync(nsum, 0, 400000, stream);
  qproj_kernel<<<dim3(16), dim3(128), 0, stream>>>(q, gw1, gb1, Qg);
  prepack_kernel<<<dim3(1), dim3(1024), 0, stream>>>(sw1, WtG);
  nodeproj_kernel<<<dim3(1563, 4), dim3(256), 0, stream>>>(h, gw1, sw1, GA, GB, SA, SB);
  gate_kernel<<<dim3(NE / 256), dim3(256), 0, stream>>>(eidx, ebat, GA, GB, Qg, gw2, gb2, gateb);
  score_kernel<<<dim3(NE / 256), dim3(256), 0, stream>>>(
      e, eidx, SA, SB, WtG, sb1, sw2, sb2, gateb, out, nsum);
  norm_kernel<<<dim3(NE / 256), dim3(256), 0, stream>>>(eidx, nsum, out);
}

// Round 6
// 641.405 us; speedup vs baseline: 1.4141x; 1.4141x over previous
//
#include <hip/hip_runtime.h>
#include <hip/hip_bf16.h>

#define NN 100000
#define NE 1600000
// D_H = D_E = D_Q = 64, D_HID = 128, N_GRAPHS = 16

typedef __attribute__((ext_vector_type(8))) unsigned short ushort8v;
typedef __attribute__((ext_vector_type(4))) unsigned short ushort4v;
typedef __attribute__((ext_vector_type(8))) short short8v;
typedef __attribute__((ext_vector_type(4))) float f32x4;

__device__ __forceinline__ float b2f(unsigned short u) {
  return __uint_as_float(((unsigned)u) << 16);
}
// f32 -> bf16 bits, round-to-nearest-even
__device__ __forceinline__ short f2bs(float f) {
  unsigned u = __float_as_uint(f);
  unsigned r = (u + 0x7FFFu + ((u >> 16) & 1u)) >> 16;
  return (short)r;
}

// Qg[g][j] = gate_b1[j] + sum_k q[g][k] * gate_w1[128+k][j]
__global__ void qproj_kernel(const float* __restrict__ q,
                             const float* __restrict__ gw1,
                             const float* __restrict__ gb1,
                             float* __restrict__ Qg) {
  int g = blockIdx.x, j = threadIdx.x;
  float acc = gb1[j];
  for (int k = 0; k < 64; ++k) acc += q[g * 64 + k] * gw1[(128 + k) * 128 + j];
  Qg[g * 128 + j] = acc;
}

// Prepack score_w1 e-part (rows 128..191) into bf16 MFMA A-fragments.
// Fragment (t, ks), lane l=(qg,cl): elem j = sw1[(128+ks*32+qg*8+j)*128 + t*16+cl]
__global__ __launch_bounds__(1024) void prepack_kernel(
    const float* __restrict__ sw1, short8v* __restrict__ WtG) {
  int tid = threadIdx.x;
  int t = tid >> 7, ks = (tid >> 6) & 1, lane = tid & 63;
  int qg = lane >> 4, cl = lane & 15;
  short8v fr;
#pragma unroll
  for (int j = 0; j < 8; ++j)
    fr[j] = f2bs(sw1[(128 + ks * 32 + qg * 8 + j) * 128 + t * 16 + cl]);
  WtG[tid] = fr;
}

// Node projections -> 4 separate bf16 arrays [N][128]:
// part 0: GA = h @ gw1[r0..63]    part 1: SA = h @ sw1[r0..63]
// part 2: GB = h @ gw1[r64..127]  part 3: SB = h @ sw1[r64..127]
__global__ __launch_bounds__(256) void nodeproj_kernel(
    const float* __restrict__ h, const float* __restrict__ gw1,
    const float* __restrict__ sw1, __hip_bfloat16* __restrict__ GA,
    __hip_bfloat16* __restrict__ GB, __hip_bfloat16* __restrict__ SA,
    __hip_bfloat16* __restrict__ SB) {
  __shared__ float hs[64][64];   // [k][n]
  __shared__ float Ws[64][128];  // [k][c]
  int part = blockIdx.y;
  const float* W = (part & 1) ? sw1 : gw1;
  int roff = (part >= 2) ? 64 : 0;
  __hip_bfloat16* outp = (part == 0) ? GA : (part == 1) ? SA : (part == 2) ? GB : SB;
  int n0 = blockIdx.x * 64;
  int t = threadIdx.x;

  {
    int n = t & 63, kc = t >> 6;
    int gn = n0 + n;
#pragma unroll
    for (int i = 0; i < 4; ++i) {
      int k = kc * 16 + i * 4;
      float4 hv = make_float4(0.f, 0.f, 0.f, 0.f);
      if (gn < NN) hv = *(const float4*)&h[gn * 64 + k];
      hs[k + 0][n] = hv.x; hs[k + 1][n] = hv.y;
      hs[k + 2][n] = hv.z; hs[k + 3][n] = hv.w;
    }
  }
  {
    const float* Wb = W + roff * 128;
    float* wsf = &Ws[0][0];
#pragma unroll
    for (int i = 0; i < 8; ++i) {
      int flat = (i * 256 + t) * 4;
      *(float4*)&wsf[flat] = *(const float4*)&Wb[flat];
    }
  }
  __syncthreads();

  int tx = t & 31, ty = t >> 5;
  float acc[8][4] = {};
#pragma unroll 4
  for (int k = 0; k < 64; ++k) {
    float hn[8];
    *(float4*)&hn[0] = *(const float4*)&hs[k][ty * 8];
    *(float4*)&hn[4] = *(const float4*)&hs[k][ty * 8 + 4];
    float wv[4];
#pragma unroll
    for (int i = 0; i < 4; ++i) wv[i] = Ws[k][tx + 32 * i];
#pragma unroll
    for (int j = 0; j < 8; ++j)
#pragma unroll
      for (int i = 0; i < 4; ++i) acc[j][i] += hn[j] * wv[i];
  }
#pragma unroll
  for (int j = 0; j < 8; ++j) {
    int gn = n0 + ty * 8 + j;
    if (gn < NN) {
#pragma unroll
      for (int i = 0; i < 4; ++i)
        outp[(size_t)gn * 128 + tx + 32 * i] = __float2bfloat16(acc[j][i]);
    }
  }
}

// Gate kernel v2: one thread per edge; gathers batched in halves of 16
// independent 16B loads for MLP. Hot set = GA+GB (51MB).
__global__ __launch_bounds__(256) void gate_kernel(
    const int* __restrict__ eidx, const int* __restrict__ ebat,
    const __hip_bfloat16* __restrict__ GA, const __hip_bfloat16* __restrict__ GB,
    const float* __restrict__ Qg, const float* __restrict__ gw2,
    const float* __restrict__ gb2, float* __restrict__ gate) {
  int ee = blockIdx.x * 256 + threadIdx.x;
  int src = eidx[ee], dst = eidx[NE + ee], g = ebat[ee];
  const ushort8v* ga = (const ushort8v*)((const unsigned short*)GA + (size_t)src * 128);
  const ushort8v* gb = (const ushort8v*)((const unsigned short*)GB + (size_t)dst * 128);
  const f32x4* qv = (const f32x4*)(Qg + g * 128);
  const f32x4* w2 = (const f32x4*)gw2;
  float gacc = 0.f;
#pragma unroll
  for (int h = 0; h < 2; ++h) {
    // batch: 16 independent 16B loads, then compute
    ushort8v av[8], bv[8];
#pragma unroll
    for (int k = 0; k < 8; ++k) { av[k] = ga[h * 8 + k]; bv[k] = gb[h * 8 + k]; }
#pragma unroll
    for (int k = 0; k < 8; ++k) {
      int jo = h * 8 + k;
#pragma unroll
      for (int half = 0; half < 2; ++half) {
        f32x4 qq = qv[2 * jo + half];
        f32x4 ww = w2[2 * jo + half];
#pragma unroll
        for (int ii = 0; ii < 4; ++ii) {
          float x = b2f(av[k][half * 4 + ii]) + b2f(bv[k][half * 4 + ii]) + qq[ii];
          gacc = fmaf(fmaxf(x, 0.f), ww[ii], gacc);
        }
      }
    }
  }
  gate[ee] = 1.f / (1.f + __expf(-(gacc + gb2[0])));
}

// Score kernel v3: swapped MFMA (W-frags as A from LDS, e-frags as B) ->
// lane cl owns edge cl, dims t*16+qg*4+i. All 16 sa/sb gathers per rt are
// independent 8B loads issued before the t-loop. Fused exp + atomicAdd.
__global__ __launch_bounds__(256) void score_kernel(
    const float* __restrict__ e, const int* __restrict__ eidx,
    const __hip_bfloat16* __restrict__ SA, const __hip_bfloat16* __restrict__ SB,
    const short8v* __restrict__ WtG, const float* __restrict__ sb1,
    const float* __restrict__ sw2, const float* __restrict__ sb2,
    const float* __restrict__ gate, float* __restrict__ out,
    float* __restrict__ nsum) {
  __shared__ short8v WtS[1024];            // 16 KB W fragments
  __shared__ float sb1S[128], sw2S[128];   // 1 KB biases/weights
  const int tid = threadIdx.x;
  const int w = tid >> 6, lane = tid & 63;
  const int qg = lane >> 4, cl = lane & 15;
  const int EB = blockIdx.x * 256 + w * 64;
  const unsigned short* SAU = (const unsigned short*)SA;
  const unsigned short* SBU = (const unsigned short*)SB;
  const float sb2v = sb2[0];

  {  // stage W fragments + small vectors
    const f32x4* s4 = (const f32x4*)WtG;
    f32x4* d4 = (f32x4*)WtS;
#pragma unroll
    for (int i = 0; i < 4; ++i) d4[tid + i * 256] = s4[tid + i * 256];
    if (tid < 128) { sb1S[tid] = sb1[tid]; sw2S[tid] = sw2[tid]; }
  }
  __syncthreads();

#pragma unroll 1
  for (int rt = 0; rt < 4; ++rt) {
    const int erow = EB + rt * 16 + cl;  // this lane's edge
    const int srcv = eidx[erow];
    const int dstv = eidx[NE + erow];

    // B fragment: e row of this edge, k-slice per qg (f32 -> bf16)
    const float* ap = e + (size_t)erow * 64 + qg * 8;
    f32x4 f0 = __builtin_nontemporal_load((const f32x4*)(ap + 0));
    f32x4 f1 = __builtin_nontemporal_load((const f32x4*)(ap + 4));
    f32x4 f2 = __builtin_nontemporal_load((const f32x4*)(ap + 32));
    f32x4 f3 = __builtin_nontemporal_load((const f32x4*)(ap + 36));
    short8v b0, b1;
    b0[0] = f2bs(f0.x); b0[1] = f2bs(f0.y); b0[2] = f2bs(f0.z); b0[3] = f2bs(f0.w);
    b0[4] = f2bs(f1.x); b0[5] = f2bs(f1.y); b0[6] = f2bs(f1.z); b0[7] = f2bs(f1.w);
    b1[0] = f2bs(f2.x); b1[1] = f2bs(f2.y); b1[2] = f2bs(f2.z); b1[3] = f2bs(f2.w);
    b1[4] = f2bs(f3.x); b1[5] = f2bs(f3.y); b1[6] = f2bs(f3.z); b1[7] = f2bs(f3.w);

    // issue ALL 16 gathers for this rt (independent 8B loads)
    ushort4v sav[8], sbv[8];
    const unsigned short* sr = SAU + (size_t)srcv * 128 + qg * 4;
    const unsigned short* dr = SBU + (size_t)dstv * 128 + qg * 4;
#pragma unroll
    for (int t = 0; t < 8; ++t) {
      sav[t] = *(const ushort4v*)(sr + t * 16);
      sbv[t] = *(const ushort4v*)(dr + t * 16);
    }

    float part = 0.f;
#pragma unroll
    for (int t = 0; t < 8; ++t) {
      short8v Aw0 = WtS[(t * 2 + 0) * 64 + lane];
      short8v Aw1 = WtS[(t * 2 + 1) * 64 + lane];
      f32x4 acc = (f32x4){0.f, 0.f, 0.f, 0.f};
      acc = __builtin_amdgcn_mfma_f32_16x16x32_bf16(Aw0, b0, acc, 0, 0, 0);
      acc = __builtin_amdgcn_mfma_f32_16x16x32_bf16(Aw1, b1, acc, 0, 0, 0);
      f32x4 b1v = *(const f32x4*)&sb1S[t * 16 + qg * 4];
      f32x4 w2v = *(const f32x4*)&sw2S[t * 16 + qg * 4];
#pragma unroll
      for (int i = 0; i < 4; ++i) {
        float hv = acc[i] + b2f(sav[t][i]) + b2f(sbv[t][i]) + b1v[i];
        part = fmaf(fmaxf(hv, 0.f), w2v[i], part);
      }
    }
    // reduce over qg groups -> full 128-dim sum per edge
    part += __shfl_xor(part, 16, 64);
    part += __shfl_xor(part, 32, 64);
    if (lane < 16) {
      int E = EB + rt * 16 + cl;
      float ex = __expf(gate[E] * (part + sb2v));
      out[E] = ex;
      atomicAdd(&nsum[dstv], ex);
    }
  }
}

__global__ __launch_bounds__(256) void norm_kernel(
    const int* __restrict__ eidx, const float* __restrict__ nodesum,
    float* __restrict__ out) {
  int ee = blockIdx.x * 256 + threadIdx.x;
  int dst = eidx[NE + ee];
  out[ee] = out[ee] / fmaxf(nodesum[dst], 1e-9f);
}

extern "C" void kernel_launch(void* const* d_in, const int* in_sizes, int n_in,
                              void* d_out, int out_size, void* d_ws, size_t ws_size,
                              hipStream_t stream) {
  const float* h   = (const float*)d_in[0];
  const float* e   = (const float*)d_in[1];
  const float* q   = (const float*)d_in[2];
  const int* eidx  = (const int*)d_in[3];
  const int* ebat  = (const int*)d_in[4];
  const float* gw1 = (const float*)d_in[5];
  const float* gb1 = (const float*)d_in[6];
  const float* gw2 = (const float*)d_in[7];
  const float* gb2 = (const float*)d_in[8];
  const float* sw1 = (const float*)d_in[9];
  const float* sb1 = (const float*)d_in[10];
  const float* sw2 = (const float*)d_in[11];
  const float* sb2 = (const float*)d_in[12];
  float* out = (float*)d_out;

  char* ws = (char*)d_ws;
  // 4 x 25.6MB projections | Qg 8KB | WtG 16KB | gate 6.4MB | nsum 400KB
  __hip_bfloat16* GA = (__hip_bfloat16*)ws;
  __hip_bfloat16* GB = (__hip_bfloat16*)(ws + 25600000);
  __hip_bfloat16* SA = (__hip_bfloat16*)(ws + 51200000);
  __hip_bfloat16* SB = (__hip_bfloat16*)(ws + 76800000);
  float* Qg    = (float*)(ws + 102400000);
  short8v* WtG = (short8v*)(ws + 102400000 + 8192);
  float* gateb = (float*)(ws + 102400000 + 8192 + 16384);
  float* nsum  = (float*)(ws + 102400000 + 8192 + 16384 + 6400000);

  (void)hipMemsetAsync(nsum, 0, 400000, stream);
  qproj_kernel<<<dim3(16), dim3(128), 0, stream>>>(q, gw1, gb1, Qg);
  prepack_kernel<<<dim3(1), dim3(1024), 0, stream>>>(sw1, WtG);
  nodeproj_kernel<<<dim3(1563, 4), dim3(256), 0, stream>>>(h, gw1, sw1, GA, GB, SA, SB);
  gate_kernel<<<dim3(NE / 256), dim3(256), 0, stream>>>(eidx, ebat, GA, GB, Qg, gw2, gb2, gateb);
  score_kernel<<<dim3(NE / 256), dim3(256), 0, stream>>>(
      e, eidx, SA, SB, WtG, sb1, sw2, sb2, gateb, out, nsum);
  norm_kernel<<<dim3(NE / 256), dim3(256), 0, stream>>>(eidx, nsum, out);
}

// Round 7
// 605.735 us; speedup vs baseline: 1.4974x; 1.0589x over previous
//
#include <hip/hip_runtime.h>
#include <hip/hip_bf16.h>

#define NN 100000
#define NE 1600000
// D_H = D_E = D_Q = 64, D_HID = 128, N_GRAPHS = 16

typedef __attribute__((ext_vector_type(8))) unsigned short ushort8v;
typedef __attribute__((ext_vector_type(4))) unsigned short ushort4v;
typedef __attribute__((ext_vector_type(8))) short short8v;
typedef __attribute__((ext_vector_type(4))) float f32x4;

__device__ __forceinline__ float b2f(unsigned short u) {
  return __uint_as_float(((unsigned)u) << 16);
}
// f32 -> bf16 bits, round-to-nearest-even
__device__ __forceinline__ short f2bs(float f) {
  unsigned u = __float_as_uint(f);
  unsigned r = (u + 0x7FFFu + ((u >> 16) & 1u)) >> 16;
  return (short)r;
}

// Qg[g][j] = gate_b1[j] + sum_k q[g][k] * gate_w1[128+k][j]
__global__ void qproj_kernel(const float* __restrict__ q,
                             const float* __restrict__ gw1,
                             const float* __restrict__ gb1,
                             float* __restrict__ Qg) {
  int g = blockIdx.x, j = threadIdx.x;
  float acc = gb1[j];
  for (int k = 0; k < 64; ++k) acc += q[g * 64 + k] * gw1[(128 + k) * 128 + j];
  Qg[g * 128 + j] = acc;
}

// Prepack score_w1 e-part (rows 128..191) into bf16 MFMA A-fragments.
// Fragment (t, ks), lane l=(qg,cl): elem j = sw1[(128+ks*32+qg*8+j)*128 + t*16+cl]
__global__ __launch_bounds__(1024) void prepack_kernel(
    const float* __restrict__ sw1, short8v* __restrict__ WtG) {
  int tid = threadIdx.x;
  int t = tid >> 7, ks = (tid >> 6) & 1, lane = tid & 63;
  int qg = lane >> 4, cl = lane & 15;
  short8v fr;
#pragma unroll
  for (int j = 0; j < 8; ++j)
    fr[j] = f2bs(sw1[(128 + ks * 32 + qg * 8 + j) * 128 + t * 16 + cl]);
  WtG[tid] = fr;
}

// Node projections -> 4 separate bf16 arrays [N][128]:
// part 0: GA = h @ gw1[r0..63]    part 1: SA = h @ sw1[r0..63]
// part 2: GB = h @ gw1[r64..127]  part 3: SB = h @ sw1[r64..127]
__global__ __launch_bounds__(256) void nodeproj_kernel(
    const float* __restrict__ h, const float* __restrict__ gw1,
    const float* __restrict__ sw1, __hip_bfloat16* __restrict__ GA,
    __hip_bfloat16* __restrict__ GB, __hip_bfloat16* __restrict__ SA,
    __hip_bfloat16* __restrict__ SB) {
  __shared__ float hs[64][64];   // [k][n]
  __shared__ float Ws[64][128];  // [k][c]
  int part = blockIdx.y;
  const float* W = (part & 1) ? sw1 : gw1;
  int roff = (part >= 2) ? 64 : 0;
  __hip_bfloat16* outp = (part == 0) ? GA : (part == 1) ? SA : (part == 2) ? GB : SB;
  int n0 = blockIdx.x * 64;
  int t = threadIdx.x;

  {
    int n = t & 63, kc = t >> 6;
    int gn = n0 + n;
#pragma unroll
    for (int i = 0; i < 4; ++i) {
      int k = kc * 16 + i * 4;
      float4 hv = make_float4(0.f, 0.f, 0.f, 0.f);
      if (gn < NN) hv = *(const float4*)&h[gn * 64 + k];
      hs[k + 0][n] = hv.x; hs[k + 1][n] = hv.y;
      hs[k + 2][n] = hv.z; hs[k + 3][n] = hv.w;
    }
  }
  {
    const float* Wb = W + roff * 128;
    float* wsf = &Ws[0][0];
#pragma unroll
    for (int i = 0; i < 8; ++i) {
      int flat = (i * 256 + t) * 4;
      *(float4*)&wsf[flat] = *(const float4*)&Wb[flat];
    }
  }
  __syncthreads();

  int tx = t & 31, ty = t >> 5;
  float acc[8][4] = {};
#pragma unroll 4
  for (int k = 0; k < 64; ++k) {
    float hn[8];
    *(float4*)&hn[0] = *(const float4*)&hs[k][ty * 8];
    *(float4*)&hn[4] = *(const float4*)&hs[k][ty * 8 + 4];
    float wv[4];
#pragma unroll
    for (int i = 0; i < 4; ++i) wv[i] = Ws[k][tx + 32 * i];
#pragma unroll
    for (int j = 0; j < 8; ++j)
#pragma unroll
      for (int i = 0; i < 4; ++i) acc[j][i] += hn[j] * wv[i];
  }
#pragma unroll
  for (int j = 0; j < 8; ++j) {
    int gn = n0 + ty * 8 + j;
    if (gn < NN) {
#pragma unroll
      for (int i = 0; i < 4; ++i)
        outp[(size_t)gn * 128 + tx + 32 * i] = __float2bfloat16(acc[j][i]);
    }
  }
}

// Fused edge kernel: gate + score + exp + atomicAdd in one pass.
// 4 waves x 64 edges; lane (qg,cl): edge cl (of 16 per rt), hidden dims
// t*16+qg*4+i. Score e-part via swapped MFMA (W-frags A from LDS, e-frag B).
// Per rt: 4 e-loads + 32 independent 8B gathers (GA/GB/SA/SB) upfront.
__global__ __launch_bounds__(256) void edge_kernel(
    const float* __restrict__ e, const int* __restrict__ eidx,
    const int* __restrict__ ebat,
    const __hip_bfloat16* __restrict__ GA, const __hip_bfloat16* __restrict__ GB,
    const __hip_bfloat16* __restrict__ SA, const __hip_bfloat16* __restrict__ SB,
    const float* __restrict__ Qg, const short8v* __restrict__ WtG,
    const float* __restrict__ sb1, const float* __restrict__ gw2,
    const float* __restrict__ gb2, const float* __restrict__ sw2,
    const float* __restrict__ sb2, float* __restrict__ out,
    float* __restrict__ nsum) {
  __shared__ short8v WtS[1024];   // 16 KB W fragments
  __shared__ f32x4 QgS[512];      // 8 KB: Qg as f32x4[g*32 + t*4 + qg]
  __shared__ f32x4 gw2S[32], sb1S[32], sw2S[32];  // 1.5 KB
  const int tid = threadIdx.x;
  const int w = tid >> 6, lane = tid & 63;
  const int qg = lane >> 4, cl = lane & 15;
  const int EB = blockIdx.x * 256 + w * 64;
  const unsigned short* GAU = (const unsigned short*)GA;
  const unsigned short* GBU = (const unsigned short*)GB;
  const unsigned short* SAU = (const unsigned short*)SA;
  const unsigned short* SBU = (const unsigned short*)SB;
  const float sb2v = sb2[0], gb2v = gb2[0];

  {  // stage LDS
    const f32x4* s4 = (const f32x4*)WtG;
    f32x4* d4 = (f32x4*)WtS;
#pragma unroll
    for (int i = 0; i < 4; ++i) d4[tid + i * 256] = s4[tid + i * 256];
    const f32x4* q4 = (const f32x4*)Qg;
    QgS[tid] = q4[tid];
    QgS[tid + 256] = q4[tid + 256];
    if (tid < 32) {
      gw2S[tid] = ((const f32x4*)gw2)[tid];
      sb1S[tid] = ((const f32x4*)sb1)[tid];
      sw2S[tid] = ((const f32x4*)sw2)[tid];
    }
  }
  __syncthreads();

#pragma unroll 1
  for (int rt = 0; rt < 4; ++rt) {
    const int erow = EB + rt * 16 + cl;  // this lane's edge
    const int srcv = eidx[erow];
    const int dstv = eidx[NE + erow];
    const int g = ebat[erow];

    // B fragment: e row of this edge, k-slice per qg (f32 -> bf16, nt)
    const float* ap = e + (size_t)erow * 64 + qg * 8;
    f32x4 f0 = __builtin_nontemporal_load((const f32x4*)(ap + 0));
    f32x4 f1 = __builtin_nontemporal_load((const f32x4*)(ap + 4));
    f32x4 f2 = __builtin_nontemporal_load((const f32x4*)(ap + 32));
    f32x4 f3 = __builtin_nontemporal_load((const f32x4*)(ap + 36));

    // issue ALL 32 gathers for this rt (independent 8B loads)
    const unsigned short* sr = SAU + (size_t)srcv * 128 + qg * 4;
    const unsigned short* dr = SBU + (size_t)dstv * 128 + qg * 4;
    const unsigned short* gr = GAU + (size_t)srcv * 128 + qg * 4;
    const unsigned short* hr = GBU + (size_t)dstv * 128 + qg * 4;
    ushort4v sav[8], sbv[8], gav[8], gbv[8];
#pragma unroll
    for (int t = 0; t < 8; ++t) {
      sav[t] = *(const ushort4v*)(sr + t * 16);
      sbv[t] = *(const ushort4v*)(dr + t * 16);
      gav[t] = *(const ushort4v*)(gr + t * 16);
      gbv[t] = *(const ushort4v*)(hr + t * 16);
    }

    short8v b0, b1;
    b0[0] = f2bs(f0.x); b0[1] = f2bs(f0.y); b0[2] = f2bs(f0.z); b0[3] = f2bs(f0.w);
    b0[4] = f2bs(f1.x); b0[5] = f2bs(f1.y); b0[6] = f2bs(f1.z); b0[7] = f2bs(f1.w);
    b1[0] = f2bs(f2.x); b1[1] = f2bs(f2.y); b1[2] = f2bs(f2.z); b1[3] = f2bs(f2.w);
    b1[4] = f2bs(f3.x); b1[5] = f2bs(f3.y); b1[6] = f2bs(f3.z); b1[7] = f2bs(f3.w);

    float part = 0.f, gpart = 0.f;
#pragma unroll
    for (int t = 0; t < 8; ++t) {
      short8v Aw0 = WtS[(t * 2 + 0) * 64 + lane];
      short8v Aw1 = WtS[(t * 2 + 1) * 64 + lane];
      f32x4 acc = (f32x4){0.f, 0.f, 0.f, 0.f};
      acc = __builtin_amdgcn_mfma_f32_16x16x32_bf16(Aw0, b0, acc, 0, 0, 0);
      acc = __builtin_amdgcn_mfma_f32_16x16x32_bf16(Aw1, b1, acc, 0, 0, 0);
      f32x4 bb = sb1S[t * 4 + qg];
      f32x4 ww = sw2S[t * 4 + qg];
      f32x4 qv = QgS[g * 32 + t * 4 + qg];
      f32x4 g2 = gw2S[t * 4 + qg];
#pragma unroll
      for (int i = 0; i < 4; ++i) {
        float sx = acc[i] + b2f(sav[t][i]) + b2f(sbv[t][i]) + bb[i];
        part = fmaf(fmaxf(sx, 0.f), ww[i], part);
        float gx = b2f(gav[t][i]) + b2f(gbv[t][i]) + qv[i];
        gpart = fmaf(fmaxf(gx, 0.f), g2[i], gpart);
      }
    }
    // reduce over qg groups -> full 128-dim sums per edge
    part += __shfl_xor(part, 16, 64);
    part += __shfl_xor(part, 32, 64);
    gpart += __shfl_xor(gpart, 16, 64);
    gpart += __shfl_xor(gpart, 32, 64);
    if (lane < 16) {
      int E = EB + rt * 16 + cl;
      float gate = 1.f / (1.f + __expf(-(gpart + gb2v)));
      float ex = __expf(gate * (part + sb2v));
      out[E] = ex;
      atomicAdd(&nsum[dstv], ex);
    }
  }
}

__global__ __launch_bounds__(256) void norm_kernel(
    const int* __restrict__ eidx, const float* __restrict__ nodesum,
    float* __restrict__ out) {
  int ee = blockIdx.x * 256 + threadIdx.x;
  int dst = eidx[NE + ee];
  out[ee] = out[ee] / fmaxf(nodesum[dst], 1e-9f);
}

extern "C" void kernel_launch(void* const* d_in, const int* in_sizes, int n_in,
                              void* d_out, int out_size, void* d_ws, size_t ws_size,
                              hipStream_t stream) {
  const float* h   = (const float*)d_in[0];
  const float* e   = (const float*)d_in[1];
  const float* q   = (const float*)d_in[2];
  const int* eidx  = (const int*)d_in[3];
  const int* ebat  = (const int*)d_in[4];
  const float* gw1 = (const float*)d_in[5];
  const float* gb1 = (const float*)d_in[6];
  const float* gw2 = (const float*)d_in[7];
  const float* gb2 = (const float*)d_in[8];
  const float* sw1 = (const float*)d_in[9];
  const float* sb1 = (const float*)d_in[10];
  const float* sw2 = (const float*)d_in[11];
  const float* sb2 = (const float*)d_in[12];
  float* out = (float*)d_out;

  char* ws = (char*)d_ws;
  // 4 x 25.6MB projections | Qg 8KB | WtG 16KB | nsum 400KB
  __hip_bfloat16* GA = (__hip_bfloat16*)ws;
  __hip_bfloat16* GB = (__hip_bfloat16*)(ws + 25600000);
  __hip_bfloat16* SA = (__hip_bfloat16*)(ws + 51200000);
  __hip_bfloat16* SB = (__hip_bfloat16*)(ws + 76800000);
  float* Qg    = (float*)(ws + 102400000);
  short8v* WtG = (short8v*)(ws + 102400000 + 8192);
  float* nsum  = (float*)(ws + 102400000 + 8192 + 16384);

  (void)hipMemsetAsync(nsum, 0, 400000, stream);
  qproj_kernel<<<dim3(16), dim3(128), 0, stream>>>(q, gw1, gb1, Qg);
  prepack_kernel<<<dim3(1), dim3(1024), 0, stream>>>(sw1, WtG);
  nodeproj_kernel<<<dim3(1563, 4), dim3(256), 0, stream>>>(h, gw1, sw1, GA, GB, SA, SB);
  edge_kernel<<<dim3(NE / 256), dim3(256), 0, stream>>>(
      e, eidx, ebat, GA, GB, SA, SB, Qg, WtG, sb1, gw2, gb2, sw2, sb2, out, nsum);
  norm_kernel<<<dim3(NE / 256), dim3(256), 0, stream>>>(eidx, nsum, out);
}

// Round 8
// 529.833 us; speedup vs baseline: 1.7119x; 1.1433x over previous
//
#include <hip/hip_runtime.h>
#include <hip/hip_bf16.h>

#define NN 100000
#define NE 1600000
// D_H = D_E = D_Q = 64, D_HID = 128, N_GRAPHS = 16

typedef __attribute__((ext_vector_type(8))) unsigned short ushort8v;
typedef __attribute__((ext_vector_type(4))) unsigned short ushort4v;
typedef __attribute__((ext_vector_type(8))) short short8v;
typedef __attribute__((ext_vector_type(4))) float f32x4;

__device__ __forceinline__ float b2f(unsigned short u) {
  return __uint_as_float(((unsigned)u) << 16);
}
// f32 -> bf16 bits, round-to-nearest-even
__device__ __forceinline__ short f2bs(float f) {
  unsigned u = __float_as_uint(f);
  unsigned r = (u + 0x7FFFu + ((u >> 16) & 1u)) >> 16;
  return (short)r;
}

// Qg[g][j] = gate_b1[j] + sum_k q[g][k] * gate_w1[128+k][j]
__global__ void qproj_kernel(const float* __restrict__ q,
                             const float* __restrict__ gw1,
                             const float* __restrict__ gb1,
                             float* __restrict__ Qg) {
  int g = blockIdx.x, j = threadIdx.x;
  float acc = gb1[j];
  for (int k = 0; k < 64; ++k) acc += q[g * 64 + k] * gw1[(128 + k) * 128 + j];
  Qg[g * 128 + j] = acc;
}

// Prepack score_w1 e-part (rows 128..191) into bf16 MFMA A-fragments.
// Fragment (t, ks), lane l=(qg,cl): elem j = sw1[(128+ks*32+qg*8+j)*128 + t*16+cl]
__global__ __launch_bounds__(1024) void prepack_kernel(
    const float* __restrict__ sw1, short8v* __restrict__ WtG) {
  int tid = threadIdx.x;
  int t = tid >> 7, ks = (tid >> 6) & 1, lane = tid & 63;
  int qg = lane >> 4, cl = lane & 15;
  short8v fr;
#pragma unroll
  for (int j = 0; j < 8; ++j)
    fr[j] = f2bs(sw1[(128 + ks * 32 + qg * 8 + j) * 128 + t * 16 + cl]);
  WtG[tid] = fr;
}

// Node projections -> 4 separate bf16 arrays [N][128]:
// part 0: GA = h @ gw1[r0..63]    part 1: SA = h @ sw1[r0..63]
// part 2: GB = h @ gw1[r64..127]  part 3: SB = h @ sw1[r64..127]
__global__ __launch_bounds__(256) void nodeproj_kernel(
    const float* __restrict__ h, const float* __restrict__ gw1,
    const float* __restrict__ sw1, __hip_bfloat16* __restrict__ GA,
    __hip_bfloat16* __restrict__ GB, __hip_bfloat16* __restrict__ SA,
    __hip_bfloat16* __restrict__ SB) {
  __shared__ float hs[64][64];   // [k][n]
  __shared__ float Ws[64][128];  // [k][c]
  int part = blockIdx.y;
  const float* W = (part & 1) ? sw1 : gw1;
  int roff = (part >= 2) ? 64 : 0;
  __hip_bfloat16* outp = (part == 0) ? GA : (part == 1) ? SA : (part == 2) ? GB : SB;
  int n0 = blockIdx.x * 64;
  int t = threadIdx.x;

  {
    int n = t & 63, kc = t >> 6;
    int gn = n0 + n;
#pragma unroll
    for (int i = 0; i < 4; ++i) {
      int k = kc * 16 + i * 4;
      float4 hv = make_float4(0.f, 0.f, 0.f, 0.f);
      if (gn < NN) hv = *(const float4*)&h[gn * 64 + k];
      hs[k + 0][n] = hv.x; hs[k + 1][n] = hv.y;
      hs[k + 2][n] = hv.z; hs[k + 3][n] = hv.w;
    }
  }
  {
    const float* Wb = W + roff * 128;
    float* wsf = &Ws[0][0];
#pragma unroll
    for (int i = 0; i < 8; ++i) {
      int flat = (i * 256 + t) * 4;
      *(float4*)&wsf[flat] = *(const float4*)&Wb[flat];
    }
  }
  __syncthreads();

  int tx = t & 31, ty = t >> 5;
  float acc[8][4] = {};
#pragma unroll 4
  for (int k = 0; k < 64; ++k) {
    float hn[8];
    *(float4*)&hn[0] = *(const float4*)&hs[k][ty * 8];
    *(float4*)&hn[4] = *(const float4*)&hs[k][ty * 8 + 4];
    float wv[4];
#pragma unroll
    for (int i = 0; i < 4; ++i) wv[i] = Ws[k][tx + 32 * i];
#pragma unroll
    for (int j = 0; j < 8; ++j)
#pragma unroll
      for (int i = 0; i < 4; ++i) acc[j][i] += hn[j] * wv[i];
  }
#pragma unroll
  for (int j = 0; j < 8; ++j) {
    int gn = n0 + ty * 8 + j;
    if (gn < NN) {
#pragma unroll
      for (int i = 0; i < 4; ++i)
        outp[(size_t)gn * 128 + tx + 32 * i] = __float2bfloat16(acc[j][i]);
    }
  }
}

// Fused edge kernel v2: gate + score + exp + atomicAdd in one pass.
// 4 waves x 64 edges; lane (qg,cl): edge cl per rt. Score dims t*16+qg*4+i
// (MFMA layout, 8B gathers); gate dims 32qg..32qg+31 (4x16B gathers).
// QgS padded (stride 33) to kill 16-way bank conflicts. Index loads are
// depth-1 software-pipelined in named scalars.
__global__ __launch_bounds__(256) void edge_kernel(
    const float* __restrict__ e, const int* __restrict__ eidx,
    const int* __restrict__ ebat,
    const __hip_bfloat16* __restrict__ GA, const __hip_bfloat16* __restrict__ GB,
    const __hip_bfloat16* __restrict__ SA, const __hip_bfloat16* __restrict__ SB,
    const float* __restrict__ Qg, const short8v* __restrict__ WtG,
    const float* __restrict__ sb1, const float* __restrict__ gw2,
    const float* __restrict__ gb2, const float* __restrict__ sw2,
    const float* __restrict__ sb2, float* __restrict__ out,
    float* __restrict__ nsum) {
  __shared__ short8v WtS[1024];    // 16 KB W fragments
  __shared__ f32x4 QgS[16 * 33];   // 8.4 KB padded: row stride 33 -> 2-way max
  __shared__ f32x4 gw2S[32], sb1S[32], sw2S[32];  // 1.5 KB
  const int tid = threadIdx.x;
  const int w = tid >> 6, lane = tid & 63;
  const int qg = lane >> 4, cl = lane & 15;
  const int EB = blockIdx.x * 256 + w * 64;
  const unsigned short* GAU = (const unsigned short*)GA;
  const unsigned short* GBU = (const unsigned short*)GB;
  const unsigned short* SAU = (const unsigned short*)SA;
  const unsigned short* SBU = (const unsigned short*)SB;
  const float sb2v = sb2[0], gb2v = gb2[0];

  // prefetch rt=0 indices before staging (overlaps with LDS fill)
  int srcv = eidx[EB + cl];
  int dstv = eidx[NE + EB + cl];
  int gv   = ebat[EB + cl];

  {  // stage LDS
    const f32x4* s4 = (const f32x4*)WtG;
    f32x4* d4 = (f32x4*)WtS;
#pragma unroll
    for (int i = 0; i < 4; ++i) d4[tid + i * 256] = s4[tid + i * 256];
    const f32x4* q4 = (const f32x4*)Qg;
    QgS[(tid >> 5) * 33 + (tid & 31)] = q4[tid];
    {
      int t2 = tid + 256;
      QgS[(t2 >> 5) * 33 + (t2 & 31)] = q4[t2];
    }
    if (tid < 32) {
      gw2S[tid] = ((const f32x4*)gw2)[tid];
      sb1S[tid] = ((const f32x4*)sb1)[tid];
      sw2S[tid] = ((const f32x4*)sw2)[tid];
    }
  }
  __syncthreads();

#pragma unroll 1
  for (int rt = 0; rt < 4; ++rt) {
    const int erow = EB + rt * 16 + cl;  // this lane's edge

    // ---- issue ALL loads for this rt upfront ----
    const float* ap = e + (size_t)erow * 64 + qg * 8;
    f32x4 f0 = __builtin_nontemporal_load((const f32x4*)(ap + 0));
    f32x4 f1 = __builtin_nontemporal_load((const f32x4*)(ap + 4));
    f32x4 f2 = __builtin_nontemporal_load((const f32x4*)(ap + 32));
    f32x4 f3 = __builtin_nontemporal_load((const f32x4*)(ap + 36));

    // gate: 64B contiguous per lane (dims 32qg..32qg+31), 4+4 x16B
    const unsigned short* gr = GAU + (size_t)srcv * 128 + qg * 32;
    const unsigned short* hr = GBU + (size_t)dstv * 128 + qg * 32;
    ushort8v gav[4], gbv[4];
#pragma unroll
    for (int c = 0; c < 4; ++c) {
      gav[c] = *(const ushort8v*)(gr + c * 8);
      gbv[c] = *(const ushort8v*)(hr + c * 8);
    }
    // score: MFMA-layout dims, 8+8 x8B
    const unsigned short* sr = SAU + (size_t)srcv * 128 + qg * 4;
    const unsigned short* dr = SBU + (size_t)dstv * 128 + qg * 4;
    ushort4v sav[8], sbv[8];
#pragma unroll
    for (int t = 0; t < 8; ++t) {
      sav[t] = *(const ushort4v*)(sr + t * 16);
      sbv[t] = *(const ushort4v*)(dr + t * 16);
    }

    // prefetch next rt's indices (named scalars, no runtime indexing)
    int srcn = srcv, dstn = dstv, gn = gv;
    if (rt < 3) {
      int er2 = erow + 16;
      srcn = eidx[er2];
      dstn = eidx[NE + er2];
      gn   = ebat[er2];
    }

    // convert e to bf16 fragments while gathers are in flight
    short8v b0, b1;
    b0[0] = f2bs(f0.x); b0[1] = f2bs(f0.y); b0[2] = f2bs(f0.z); b0[3] = f2bs(f0.w);
    b0[4] = f2bs(f1.x); b0[5] = f2bs(f1.y); b0[6] = f2bs(f1.z); b0[7] = f2bs(f1.w);
    b1[0] = f2bs(f2.x); b1[1] = f2bs(f2.y); b1[2] = f2bs(f2.z); b1[3] = f2bs(f2.w);
    b1[4] = f2bs(f3.x); b1[5] = f2bs(f3.y); b1[6] = f2bs(f3.z); b1[7] = f2bs(f3.w);

    // ---- gate compute: dims 32qg+8c+k ----
    float gpart = 0.f;
#pragma unroll
    for (int c = 0; c < 4; ++c) {
      ushort8v av = gav[c], bv = gbv[c];
      f32x4 q0 = QgS[gv * 33 + qg * 8 + c * 2];
      f32x4 q1 = QgS[gv * 33 + qg * 8 + c * 2 + 1];
      f32x4 w0 = gw2S[qg * 8 + c * 2];
      f32x4 w1 = gw2S[qg * 8 + c * 2 + 1];
#pragma unroll
      for (int ii = 0; ii < 4; ++ii) {
        float x = b2f(av[ii]) + b2f(bv[ii]) + q0[ii];
        gpart = fmaf(fmaxf(x, 0.f), w0[ii], gpart);
      }
#pragma unroll
      for (int ii = 0; ii < 4; ++ii) {
        float x = b2f(av[4 + ii]) + b2f(bv[4 + ii]) + q1[ii];
        gpart = fmaf(fmaxf(x, 0.f), w1[ii], gpart);
      }
    }

    // ---- score compute: MFMA + epilogue ----
    float part = 0.f;
#pragma unroll
    for (int t = 0; t < 8; ++t) {
      short8v Aw0 = WtS[(t * 2 + 0) * 64 + lane];
      short8v Aw1 = WtS[(t * 2 + 1) * 64 + lane];
      f32x4 acc = (f32x4){0.f, 0.f, 0.f, 0.f};
      acc = __builtin_amdgcn_mfma_f32_16x16x32_bf16(Aw0, b0, acc, 0, 0, 0);
      acc = __builtin_amdgcn_mfma_f32_16x16x32_bf16(Aw1, b1, acc, 0, 0, 0);
      f32x4 bb = sb1S[t * 4 + qg];
      f32x4 ww = sw2S[t * 4 + qg];
#pragma unroll
      for (int i = 0; i < 4; ++i) {
        float sx = acc[i] + b2f(sav[t][i]) + b2f(sbv[t][i]) + bb[i];
        part = fmaf(fmaxf(sx, 0.f), ww[i], part);
      }
    }

    // ---- reduce over qg groups; finalize ----
    part += __shfl_xor(part, 16, 64);
    part += __shfl_xor(part, 32, 64);
    gpart += __shfl_xor(gpart, 16, 64);
    gpart += __shfl_xor(gpart, 32, 64);
    if (lane < 16) {
      int E = EB + rt * 16 + cl;
      float gate = 1.f / (1.f + __expf(-(gpart + gb2v)));
      float ex = __expf(gate * (part + sb2v));
      out[E] = ex;
      atomicAdd(&nsum[dstv], ex);
    }
    srcv = srcn; dstv = dstn; gv = gn;
  }
}

__global__ __launch_bounds__(256) void norm_kernel(
    const int* __restrict__ eidx, const float* __restrict__ nodesum,
    float* __restrict__ out) {
  int ee = blockIdx.x * 256 + threadIdx.x;
  int dst = eidx[NE + ee];
  out[ee] = out[ee] / fmaxf(nodesum[dst], 1e-9f);
}

extern "C" void kernel_launch(void* const* d_in, const int* in_sizes, int n_in,
                              void* d_out, int out_size, void* d_ws, size_t ws_size,
                              hipStream_t stream) {
  const float* h   = (const float*)d_in[0];
  const float* e   = (const float*)d_in[1];
  const float* q   = (const float*)d_in[2];
  const int* eidx  = (const int*)d_in[3];
  const int* ebat  = (const int*)d_in[4];
  const float* gw1 = (const float*)d_in[5];
  const float* gb1 = (const float*)d_in[6];
  const float* gw2 = (const float*)d_in[7];
  const float* gb2 = (const float*)d_in[8];
  const float* sw1 = (const float*)d_in[9];
  const float* sb1 = (const float*)d_in[10];
  const float* sw2 = (const float*)d_in[11];
  const float* sb2 = (const float*)d_in[12];
  float* out = (float*)d_out;

  char* ws = (char*)d_ws;
  // 4 x 25.6MB projections | Qg 8KB | WtG 16KB | nsum 400KB
  __hip_bfloat16* GA = (__hip_bfloat16*)ws;
  __hip_bfloat16* GB = (__hip_bfloat16*)(ws + 25600000);
  __hip_bfloat16* SA = (__hip_bfloat16*)(ws + 51200000);
  __hip_bfloat16* SB = (__hip_bfloat16*)(ws + 76800000);
  float* Qg    = (float*)(ws + 102400000);
  short8v* WtG = (short8v*)(ws + 102400000 + 8192);
  float* nsum  = (float*)(ws + 102400000 + 8192 + 16384);

  (void)hipMemsetAsync(nsum, 0, 400000, stream);
  qproj_kernel<<<dim3(16), dim3(128), 0, stream>>>(q, gw1, gb1, Qg);
  prepack_kernel<<<dim3(1), dim3(1024), 0, stream>>>(sw1, WtG);
  nodeproj_kernel<<<dim3(1563, 4), dim3(256), 0, stream>>>(h, gw1, sw1, GA, GB, SA, SB);
  edge_kernel<<<dim3(NE / 256), dim3(256), 0, stream>>>(
      e, eidx, ebat, GA, GB, SA, SB, Qg, WtG, sb1, gw2, gb2, sw2, sb2, out, nsum);
  norm_kernel<<<dim3(NE / 256), dim3(256), 0, stream>>>(eidx, nsum, out);
}